// Round 2
// baseline (454.711 us; speedup 1.0000x reference)
//
#include <hip/hip_runtime.h>
#include <hip/hip_bf16.h>
#include <stdint.h>

#define T_DIM 4096
#define H_DIM 4096
#define O_DIM 4096
#define R_DIM 16
#define S_SEG 8

typedef __attribute__((ext_vector_type(8))) short bf16x8_t;  // 8 bf16 in 4 VGPRs
typedef __attribute__((ext_vector_type(4))) float f32x4_t;

// round-to-nearest-even f32 -> bf16 (bit trick, fine for finite values)
__device__ __forceinline__ unsigned short f2bf(float f) {
  union { float f; unsigned int u; } v; v.f = f;
  unsigned int u = v.u;
  unsigned int r = (u + 0x7fffu + ((u >> 16) & 1u)) >> 16;
  return (unsigned short)r;
}

__device__ __forceinline__ void gload16(const void* g, void* l) {
  __builtin_amdgcn_global_load_lds(
      (const __attribute__((address_space(1))) unsigned int*)g,
      (__attribute__((address_space(3))) unsigned int*)l,
      16, 0, 0);
}

// ---------------- fp32 -> bf16 conversion, 8 elems/thread ----------------
__global__ __launch_bounds__(256) void cvt_kernel(const float* __restrict__ in,
                                                  unsigned short* __restrict__ out,
                                                  int n) {
  int i = (blockIdx.x * 256 + threadIdx.x) * 8;
  if (i >= n) return;
  float4 a = *(const float4*)(in + i);
  float4 b = *(const float4*)(in + i + 4);
  union { unsigned short s[8]; bf16x8_t v; } r;
  r.s[0] = f2bf(a.x); r.s[1] = f2bf(a.y); r.s[2] = f2bf(a.z); r.s[3] = f2bf(a.w);
  r.s[4] = f2bf(b.x); r.s[5] = f2bf(b.y); r.s[6] = f2bf(b.z); r.s[7] = f2bf(b.w);
  *(bf16x8_t*)(out + i) = r.v;
}

// ---------------- u[t][16] = x[t] . lora_a[l_t], plus tok_lora[t] ----------------
__global__ __launch_bounds__(256) void lora_u_kernel(const float* __restrict__ x,
                                                     const float* __restrict__ lora_a,
                                                     const int* __restrict__ indices,
                                                     float* __restrict__ u,
                                                     int* __restrict__ tok_lora) {
  int t = blockIdx.x;
  // general searchsorted(starts, t, 'right') - 1 over the first S starts
  int seg = 0;
#pragma unroll
  for (int s = 1; s < S_SEG; ++s)
    if (indices[2 * s] <= t) seg = s;
  int l = indices[2 * seg + 1];

  const float* __restrict__ a = lora_a + (size_t)l * H_DIM * R_DIM;
  const float* __restrict__ xr = x + (size_t)t * H_DIM;

  float acc[16];
#pragma unroll
  for (int r = 0; r < 16; ++r) acc[r] = 0.f;

  for (int h = threadIdx.x; h < H_DIM; h += 256) {
    float xv = xr[h];
    const float4* a4 = (const float4*)(a + (size_t)h * R_DIM);
    float4 v0 = a4[0], v1 = a4[1], v2 = a4[2], v3 = a4[3];
    acc[0]  += xv * v0.x; acc[1]  += xv * v0.y; acc[2]  += xv * v0.z; acc[3]  += xv * v0.w;
    acc[4]  += xv * v1.x; acc[5]  += xv * v1.y; acc[6]  += xv * v1.z; acc[7]  += xv * v1.w;
    acc[8]  += xv * v2.x; acc[9]  += xv * v2.y; acc[10] += xv * v2.z; acc[11] += xv * v2.w;
    acc[12] += xv * v3.x; acc[13] += xv * v3.y; acc[14] += xv * v3.z; acc[15] += xv * v3.w;
  }

  // reduce across the wave (64 lanes)
#pragma unroll
  for (int r = 0; r < 16; ++r) {
#pragma unroll
    for (int off = 32; off > 0; off >>= 1) acc[r] += __shfl_xor(acc[r], off, 64);
  }

  __shared__ float red[4][16];
  int lane = threadIdx.x & 63, wid = threadIdx.x >> 6;
  if (lane == 0) {
#pragma unroll
    for (int r = 0; r < 16; ++r) red[wid][r] = acc[r];
  }
  __syncthreads();
  if (threadIdx.x < 16) {
    int r = threadIdx.x;
    u[(size_t)t * 16 + r] = red[0][r] + red[1][r] + red[2][r] + red[3][r];
  }
  if (threadIdx.x == 0) tok_lora[t] = l;
}

// ---------------- bf16 MFMA GEMM: out = Xb @ Wb^T + bias ----------------
// m97 structure: 128x128 tile, BK=32, 4 waves (2x2), 16x16x32 MFMA,
// global_load_lds width-16 staging, 2 barriers per K-step.
__global__ __launch_bounds__(256) void gemm_kernel(const unsigned short* __restrict__ A,  // [T][H] bf16
                                                   const unsigned short* __restrict__ B,  // [O][H] bf16
                                                   const float* __restrict__ bias,
                                                   float* __restrict__ out) {
  __shared__ unsigned short lds[2 * 128 * 32];  // A tile then B tile, 16 KiB
  const int tid = threadIdx.x;
  const int lane = tid & 63;
  const int wid = tid >> 6;
  const int wr = wid >> 1;  // wave row (0..1), each wave does 64x64
  const int wc = wid & 1;   // wave col (0..1)
  const int row0 = blockIdx.y * 128;
  const int col0 = blockIdx.x * 128;

  f32x4_t acc[4][4];
#pragma unroll
  for (int m = 0; m < 4; ++m)
#pragma unroll
    for (int n = 0; n < 4; ++n) acc[m][n] = (f32x4_t){0.f, 0.f, 0.f, 0.f};

  // staging: thread -> (row = tid/4, 16B chunk = tid%4); LDS dest linear = tid*16B
  const int srow = tid >> 2;
  const int sel = (tid & 3) * 8;  // element offset within the 32-elem K row
  const unsigned short* aS0 = A + (size_t)(row0 + srow) * H_DIM + sel;
  const unsigned short* aS1 = A + (size_t)(row0 + 64 + srow) * H_DIM + sel;
  const unsigned short* bS0 = B + (size_t)(col0 + srow) * H_DIM + sel;
  const unsigned short* bS1 = B + (size_t)(col0 + 64 + srow) * H_DIM + sel;
  unsigned short* ldsA = lds;
  unsigned short* ldsB = lds + 128 * 32;
  unsigned short* dA0 = ldsA + tid * 8;
  unsigned short* dA1 = ldsA + 2048 + tid * 8;
  unsigned short* dB0 = ldsB + tid * 8;
  unsigned short* dB1 = ldsB + 2048 + tid * 8;

  // fragment read base: A[row][ (lane>>4)*8 + j ], row = wr*64 + m*16 + (lane&15)
  const unsigned short* aF = ldsA + (size_t)(wr * 64 + (lane & 15)) * 32 + (lane >> 4) * 8;
  const unsigned short* bF = ldsB + (size_t)(wc * 64 + (lane & 15)) * 32 + (lane >> 4) * 8;

  for (int kt = 0; kt < H_DIM; kt += 32) {
    gload16(aS0 + kt, dA0);
    gload16(aS1 + kt, dA1);
    gload16(bS0 + kt, dB0);
    gload16(bS1 + kt, dB1);
    __syncthreads();  // drains vmcnt(0) before barrier -> tiles visible

    bf16x8_t af[4], bfr[4];
#pragma unroll
    for (int m = 0; m < 4; ++m) af[m] = *(const bf16x8_t*)(aF + m * 16 * 32);
#pragma unroll
    for (int n = 0; n < 4; ++n) bfr[n] = *(const bf16x8_t*)(bF + n * 16 * 32);
#pragma unroll
    for (int m = 0; m < 4; ++m)
#pragma unroll
      for (int n = 0; n < 4; ++n)
        acc[m][n] = __builtin_amdgcn_mfma_f32_16x16x32_bf16(af[m], bfr[n], acc[m][n], 0, 0, 0);
    __syncthreads();  // everyone done reading before next stage overwrites
  }

  // epilogue: C/D layout col = lane&15, row = (lane>>4)*4 + reg
  const int r0 = row0 + wr * 64 + (lane >> 4) * 4;
  const int c0 = col0 + wc * 64 + (lane & 15);
  float bv[4];
#pragma unroll
  for (int n = 0; n < 4; ++n) bv[n] = bias[c0 + n * 16];
#pragma unroll
  for (int m = 0; m < 4; ++m)
#pragma unroll
    for (int n = 0; n < 4; ++n)
#pragma unroll
      for (int q = 0; q < 4; ++q) {
        int row = r0 + m * 16 + q;
        out[(size_t)row * O_DIM + (c0 + n * 16)] = acc[m][n][q] + bv[n];
      }
}

// ---------------- out[t] += u[t] . lora_b[l_t] ----------------
__global__ __launch_bounds__(256) void lora_add_kernel(float* __restrict__ out,
                                                       const float* __restrict__ u,
                                                       const int* __restrict__ tok_lora,
                                                       const float* __restrict__ lora_b) {
  int t = blockIdx.y;
  int o = blockIdx.x * 1024 + threadIdx.x * 4;
  int l = tok_lora[t];
  const float* ut = u + (size_t)t * 16;
  float uu[16];
#pragma unroll
  for (int r = 0; r < 16; ++r) uu[r] = ut[r];
  const float* b = lora_b + (size_t)l * R_DIM * O_DIM + o;
  float4 acc = *(float4*)(out + (size_t)t * O_DIM + o);
#pragma unroll
  for (int r = 0; r < 16; ++r) {
    float4 bvv = *(const float4*)(b + (size_t)r * O_DIM);
    acc.x += uu[r] * bvv.x; acc.y += uu[r] * bvv.y;
    acc.z += uu[r] * bvv.z; acc.w += uu[r] * bvv.w;
  }
  *(float4*)(out + (size_t)t * O_DIM + o) = acc;
}

extern "C" void kernel_launch(void* const* d_in, const int* in_sizes, int n_in,
                              void* d_out, int out_size, void* d_ws, size_t ws_size,
                              hipStream_t stream) {
  const float* x      = (const float*)d_in[0];
  const float* weight = (const float*)d_in[1];
  const float* bias   = (const float*)d_in[2];
  const float* lora_a = (const float*)d_in[3];
  const float* lora_b = (const float*)d_in[4];
  const int*   indices = (const int*)d_in[5];
  float* out = (float*)d_out;

  // workspace layout: Xb(32MB) | Wb(32MB) | u(256KB) | tok_lora(16KB)
  unsigned short* Xb = (unsigned short*)d_ws;
  unsigned short* Wb = Xb + (size_t)T_DIM * H_DIM;
  float* u = (float*)(Wb + (size_t)O_DIM * H_DIM);
  int* tok_lora = (int*)(u + (size_t)T_DIM * 16);

  const int nX = T_DIM * H_DIM;  // == O_DIM * H_DIM
  cvt_kernel<<<nX / 8 / 256, 256, 0, stream>>>(x, Xb, nX);
  cvt_kernel<<<nX / 8 / 256, 256, 0, stream>>>(weight, Wb, nX);
  lora_u_kernel<<<T_DIM, 256, 0, stream>>>(x, lora_a, indices, u, tok_lora);
  gemm_kernel<<<dim3(O_DIM / 128, T_DIM / 128), 256, 0, stream>>>(Xb, Wb, bias, out);
  lora_add_kernel<<<dim3(O_DIM / 1024, T_DIM), 256, 0, stream>>>(out, u, tok_lora, lora_b);
}

// Round 3
// 373.020 us; speedup vs baseline: 1.2190x; 1.2190x over previous
//
#include <hip/hip_runtime.h>
#include <hip/hip_bf16.h>
#include <stdint.h>

#define T_DIM 4096
#define H_DIM 4096
#define O_DIM 4096
#define R_DIM 16
#define S_SEG 8

typedef __attribute__((ext_vector_type(8))) short bf16x8_t;  // 8 bf16 in 4 VGPRs
typedef __attribute__((ext_vector_type(4))) float f32x4_t;

struct ushort4_t { unsigned short x, y, z, w; };

// round-to-nearest-even f32 -> bf16 (bit trick, fine for finite values)
__device__ __forceinline__ unsigned short f2bf(float f) {
  union { float f; unsigned int u; } v; v.f = f;
  unsigned int u = v.u;
  unsigned int r = (u + 0x7fffu + ((u >> 16) & 1u)) >> 16;
  return (unsigned short)r;
}

__device__ __forceinline__ void gload16(const void* g, void* l) {
  __builtin_amdgcn_global_load_lds(
      (const __attribute__((address_space(1))) unsigned int*)g,
      (__attribute__((address_space(3))) unsigned int*)l,
      16, 0, 0);
}

// segment lookup: searchsorted(starts, t, 'right') - 1; starts at indices[2s]
__device__ __forceinline__ int lora_of(const int* __restrict__ indices, int t) {
  int seg = 0;
#pragma unroll
  for (int s = 1; s < S_SEG; ++s)
    if (indices[2 * s] <= t) seg = s;
  return indices[2 * seg + 1];
}

// ---------------- fp32 -> bf16 conversion, 8 elems/thread (for W) ----------------
__global__ __launch_bounds__(256) void cvt_kernel(const float* __restrict__ in,
                                                  unsigned short* __restrict__ out,
                                                  int n) {
  int i = (blockIdx.x * 256 + threadIdx.x) * 8;
  if (i >= n) return;
  float4 a = *(const float4*)(in + i);
  float4 b = *(const float4*)(in + i + 4);
  union { unsigned short s[8]; bf16x8_t v; } r;
  r.s[0] = f2bf(a.x); r.s[1] = f2bf(a.y); r.s[2] = f2bf(a.z); r.s[3] = f2bf(a.w);
  r.s[4] = f2bf(b.x); r.s[5] = f2bf(b.y); r.s[6] = f2bf(b.z); r.s[7] = f2bf(b.w);
  *(bf16x8_t*)(out + i) = r.v;
}

// ---------------- fused: x -> Xb (bf16)  AND  u[t][16] = x[t] . lora_a[l_t] ----------------
// block = 4 consecutive tokens (same segment: 4 | 512). a-tile reads shared x4.
__global__ __launch_bounds__(256) void fused_x_kernel(const float* __restrict__ x,
                                                      const float* __restrict__ lora_a,
                                                      const int* __restrict__ indices,
                                                      unsigned short* __restrict__ Xb,
                                                      float* __restrict__ u) {
  const int t0 = blockIdx.x * 4;
  const int tid = threadIdx.x;
  const int l = lora_of(indices, t0);
  const float* __restrict__ a = lora_a + (size_t)l * H_DIM * R_DIM;

  float acc[4][16];
#pragma unroll
  for (int t = 0; t < 4; ++t)
#pragma unroll
    for (int r = 0; r < 16; ++r) acc[t][r] = 0.f;

  for (int h0 = 0; h0 < H_DIM; h0 += 1024) {
    const int h = h0 + tid * 4;
    union { float4 v; float f[4]; } xv[4];
#pragma unroll
    for (int t = 0; t < 4; ++t)
      xv[t].v = *(const float4*)(x + (size_t)(t0 + t) * H_DIM + h);
    // bf16 store (8B per token)
#pragma unroll
    for (int t = 0; t < 4; ++t) {
      ushort4_t o;
      o.x = f2bf(xv[t].f[0]); o.y = f2bf(xv[t].f[1]);
      o.z = f2bf(xv[t].f[2]); o.w = f2bf(xv[t].f[3]);
      *(ushort4_t*)(Xb + (size_t)(t0 + t) * H_DIM + h) = o;
    }
    // u accumulation: 4 h-positions, 16 ranks, 4 tokens
#pragma unroll
    for (int hh = 0; hh < 4; ++hh) {
      const float4* ap = (const float4*)(a + (size_t)(h + hh) * R_DIM);
      float4 a0 = ap[0], a1 = ap[1], a2 = ap[2], a3 = ap[3];
#pragma unroll
      for (int t = 0; t < 4; ++t) {
        float xs = xv[t].f[hh];
        acc[t][0]  += xs * a0.x; acc[t][1]  += xs * a0.y; acc[t][2]  += xs * a0.z; acc[t][3]  += xs * a0.w;
        acc[t][4]  += xs * a1.x; acc[t][5]  += xs * a1.y; acc[t][6]  += xs * a1.z; acc[t][7]  += xs * a1.w;
        acc[t][8]  += xs * a2.x; acc[t][9]  += xs * a2.y; acc[t][10] += xs * a2.z; acc[t][11] += xs * a2.w;
        acc[t][12] += xs * a3.x; acc[t][13] += xs * a3.y; acc[t][14] += xs * a3.z; acc[t][15] += xs * a3.w;
      }
    }
  }

  // reduce 64 values across each wave, then across the 4 waves via LDS
#pragma unroll
  for (int t = 0; t < 4; ++t)
#pragma unroll
    for (int r = 0; r < 16; ++r)
#pragma unroll
      for (int off = 32; off > 0; off >>= 1)
        acc[t][r] += __shfl_xor(acc[t][r], off, 64);

  __shared__ float red[4][64];
  const int lane = tid & 63, wv = tid >> 6;
  if (lane == 0) {
#pragma unroll
    for (int t = 0; t < 4; ++t)
#pragma unroll
      for (int r = 0; r < 16; ++r) red[wv][t * 16 + r] = acc[t][r];
  }
  __syncthreads();
  if (tid < 64) {
    float s = red[0][tid] + red[1][tid] + red[2][tid] + red[3][tid];
    u[(size_t)t0 * 16 + tid] = s;  // (t0+t)*16+r == t0*16 + tid, contiguous
  }
}

// ---------------- bf16 MFMA GEMM: out = Xb @ Wb^T + bias + u . lora_b[l] ----------------
// m97 structure: 128x128 tile, BK=32, 4 waves (2x2), 16x16x32 MFMA,
// global_load_lds width-16 staging, 2 barriers per K-step. LoRA-B + bias fused epilogue.
__global__ __launch_bounds__(256) void gemm_kernel(const unsigned short* __restrict__ A,  // [T][H] bf16
                                                   const unsigned short* __restrict__ B,  // [O][H] bf16
                                                   const float* __restrict__ bias,
                                                   const float* __restrict__ lora_b,
                                                   const int* __restrict__ indices,
                                                   const float* __restrict__ u,
                                                   float* __restrict__ out) {
  __shared__ unsigned short lds[2 * 128 * 32];  // A tile then B tile, 16 KiB
  const int tid = threadIdx.x;
  const int lane = tid & 63;
  const int wid = tid >> 6;
  const int wr = wid >> 1;  // wave row (0..1), each wave does 64x64
  const int wc = wid & 1;   // wave col (0..1)
  const int row0 = blockIdx.y * 128;
  const int col0 = blockIdx.x * 128;

  f32x4_t acc[4][4];
#pragma unroll
  for (int m = 0; m < 4; ++m)
#pragma unroll
    for (int n = 0; n < 4; ++n) acc[m][n] = (f32x4_t){0.f, 0.f, 0.f, 0.f};

  // staging: thread -> (row = tid/4, 16B chunk = tid%4); LDS dest linear = tid*16B
  const int srow = tid >> 2;
  const int sel = (tid & 3) * 8;  // element offset within the 32-elem K row
  const unsigned short* aS0 = A + (size_t)(row0 + srow) * H_DIM + sel;
  const unsigned short* aS1 = A + (size_t)(row0 + 64 + srow) * H_DIM + sel;
  const unsigned short* bS0 = B + (size_t)(col0 + srow) * H_DIM + sel;
  const unsigned short* bS1 = B + (size_t)(col0 + 64 + srow) * H_DIM + sel;
  unsigned short* ldsA = lds;
  unsigned short* ldsB = lds + 128 * 32;
  unsigned short* dA0 = ldsA + tid * 8;
  unsigned short* dA1 = ldsA + 2048 + tid * 8;
  unsigned short* dB0 = ldsB + tid * 8;
  unsigned short* dB1 = ldsB + 2048 + tid * 8;

  // fragment read base: A[row][ (lane>>4)*8 + j ], row = wr*64 + m*16 + (lane&15)
  const unsigned short* aF = ldsA + (size_t)(wr * 64 + (lane & 15)) * 32 + (lane >> 4) * 8;
  const unsigned short* bF = ldsB + (size_t)(wc * 64 + (lane & 15)) * 32 + (lane >> 4) * 8;

  for (int kt = 0; kt < H_DIM; kt += 32) {
    gload16(aS0 + kt, dA0);
    gload16(aS1 + kt, dA1);
    gload16(bS0 + kt, dB0);
    gload16(bS1 + kt, dB1);
    __syncthreads();  // drains vmcnt(0) before barrier -> tiles visible

    bf16x8_t af[4], bfr[4];
#pragma unroll
    for (int m = 0; m < 4; ++m) af[m] = *(const bf16x8_t*)(aF + m * 16 * 32);
#pragma unroll
    for (int n = 0; n < 4; ++n) bfr[n] = *(const bf16x8_t*)(bF + n * 16 * 32);
#pragma unroll
    for (int m = 0; m < 4; ++m)
#pragma unroll
      for (int n = 0; n < 4; ++n)
        acc[m][n] = __builtin_amdgcn_mfma_f32_16x16x32_bf16(af[m], bfr[n], acc[m][n], 0, 0, 0);
    __syncthreads();  // everyone done reading before next stage overwrites
  }

  // ---- fused LoRA-B epilogue: acc += u[row] . lora_b[l][:, col] ----
  // block's 128 rows lie in one 512-aligned segment -> uniform l
  const int l = lora_of(indices, row0);
  // reuse the 16KB LDS: u-tile 128x16 f32 (8KB) + b-tile 16x128 f32 (8KB)
  float* uLds = (float*)lds;         // [128][16]
  float* bLds = (float*)lds + 2048;  // [16][128]
  {
    const float* ug = u + (size_t)row0 * 16;
    int j = tid * 8;
    *(float4*)(uLds + j) = *(const float4*)(ug + j);
    *(float4*)(uLds + j + 4) = *(const float4*)(ug + j + 4);
    int br = tid >> 4, bc = (tid & 15) * 8;
    const float* bg = lora_b + ((size_t)l * R_DIM + br) * O_DIM + col0 + bc;
    *(float4*)(bLds + br * 128 + bc) = *(const float4*)bg;
    *(float4*)(bLds + br * 128 + bc + 4) = *(const float4*)(bg + 4);
  }
  __syncthreads();

  const int rl0 = wr * 64 + (lane >> 4) * 4;  // local row base
  const int cl0 = wc * 64 + (lane & 15);      // local col base
#pragma unroll
  for (int r = 0; r < 16; ++r) {
    float b0 = bLds[r * 128 + cl0];
    float b1 = bLds[r * 128 + cl0 + 16];
    float b2 = bLds[r * 128 + cl0 + 32];
    float b3 = bLds[r * 128 + cl0 + 48];
#pragma unroll
    for (int m = 0; m < 4; ++m)
#pragma unroll
      for (int q = 0; q < 4; ++q) {
        float uv = uLds[(rl0 + m * 16 + q) * 16 + r];
        acc[m][0][q] += uv * b0;
        acc[m][1][q] += uv * b1;
        acc[m][2][q] += uv * b2;
        acc[m][3][q] += uv * b3;
      }
  }

  // ---- bias + store: C/D layout col = lane&15, row = (lane>>4)*4 + reg ----
  const int r0 = row0 + rl0;
  const int c0 = col0 + cl0;
  float bv[4];
#pragma unroll
  for (int n = 0; n < 4; ++n) bv[n] = bias[c0 + n * 16];
#pragma unroll
  for (int m = 0; m < 4; ++m)
#pragma unroll
    for (int n = 0; n < 4; ++n)
#pragma unroll
      for (int q = 0; q < 4; ++q) {
        int row = r0 + m * 16 + q;
        out[(size_t)row * O_DIM + (c0 + n * 16)] = acc[m][n][q] + bv[n];
      }
}

extern "C" void kernel_launch(void* const* d_in, const int* in_sizes, int n_in,
                              void* d_out, int out_size, void* d_ws, size_t ws_size,
                              hipStream_t stream) {
  const float* x      = (const float*)d_in[0];
  const float* weight = (const float*)d_in[1];
  const float* bias   = (const float*)d_in[2];
  const float* lora_a = (const float*)d_in[3];
  const float* lora_b = (const float*)d_in[4];
  const int*   indices = (const int*)d_in[5];
  float* out = (float*)d_out;

  // workspace layout: Xb(32MB) | Wb(32MB) | u(256KB)
  unsigned short* Xb = (unsigned short*)d_ws;
  unsigned short* Wb = Xb + (size_t)T_DIM * H_DIM;
  float* u = (float*)(Wb + (size_t)O_DIM * H_DIM);

  const int nX = T_DIM * H_DIM;  // == O_DIM * H_DIM
  cvt_kernel<<<nX / 8 / 256, 256, 0, stream>>>(weight, Wb, nX);
  fused_x_kernel<<<T_DIM / 4, 256, 0, stream>>>(x, lora_a, indices, Xb, u);
  gemm_kernel<<<dim3(O_DIM / 128, T_DIM / 128), 256, 0, stream>>>(Xb, Wb, bias, lora_b, indices, u, out);
}

// Round 5
// 361.671 us; speedup vs baseline: 1.2573x; 1.0314x over previous
//
#include <hip/hip_runtime.h>
#include <hip/hip_bf16.h>
#include <stdint.h>

#define T_DIM 4096
#define H_DIM 4096
#define O_DIM 4096
#define R_DIM 16
#define S_SEG 8

typedef __attribute__((ext_vector_type(8))) short bf16x8_t;  // 8 bf16 in 4 VGPRs
typedef __attribute__((ext_vector_type(4))) float f32x4_t;

struct ushort4_t { unsigned short x, y, z, w; };

// round-to-nearest-even f32 -> bf16
__device__ __forceinline__ unsigned short f2bf(float f) {
  union { float f; unsigned int u; } v; v.f = f;
  unsigned int u = v.u;
  unsigned int r = (u + 0x7fffu + ((u >> 16) & 1u)) >> 16;
  return (unsigned short)r;
}

__device__ __forceinline__ void gload16(const void* g, void* l) {
  __builtin_amdgcn_global_load_lds(
      (const __attribute__((address_space(1))) unsigned int*)g,
      (__attribute__((address_space(3))) unsigned int*)l,
      16, 0, 0);
}

// segment lookup: searchsorted(starts, t, 'right') - 1; starts at indices[2s]
__device__ __forceinline__ int lora_of(const int* __restrict__ indices, int t) {
  int seg = 0;
#pragma unroll
  for (int s = 1; s < S_SEG; ++s)
    if (indices[2 * s] <= t) seg = s;
  return indices[2 * seg + 1];
}

#define SBAR() do { asm volatile("" ::: "memory"); __builtin_amdgcn_s_barrier(); asm volatile("" ::: "memory"); } while (0)
#define VMCNT8() asm volatile("s_waitcnt vmcnt(8)" ::: "memory")
#define VMCNT0() asm volatile("s_waitcnt vmcnt(0)" ::: "memory")

// ---------------- fp32 -> bf16 conversion (for W) ----------------
__global__ __launch_bounds__(256) void cvt_kernel(const float* __restrict__ in,
                                                  unsigned short* __restrict__ out,
                                                  int n) {
  int i = (blockIdx.x * 256 + threadIdx.x) * 8;
  if (i >= n) return;
  float4 a = *(const float4*)(in + i);
  float4 b = *(const float4*)(in + i + 4);
  union { unsigned short s[8]; bf16x8_t v; } r;
  r.s[0] = f2bf(a.x); r.s[1] = f2bf(a.y); r.s[2] = f2bf(a.z); r.s[3] = f2bf(a.w);
  r.s[4] = f2bf(b.x); r.s[5] = f2bf(b.y); r.s[6] = f2bf(b.z); r.s[7] = f2bf(b.w);
  *(bf16x8_t*)(out + i) = r.v;
}

// ---------------- lora_a [L][H][R] -> aT [L][R][H] (tiny, 2MB) ----------------
__global__ __launch_bounds__(256) void transpose_a(const float* __restrict__ a,
                                                   float* __restrict__ aT) {
  int l = blockIdx.y;
  const float* al = a + (size_t)l * H_DIM * R_DIM;
  float* aTl = aT + (size_t)l * H_DIM * R_DIM;
  int base = blockIdx.x * 4096;
  for (int idx = base + threadIdx.x; idx < base + 4096; idx += 256) {
    int h = idx >> 4, r = idx & 15;
    aTl[r * H_DIM + h] = al[idx];
  }
}

// ---------------- fused: x -> Xb (bf16)  AND  u[t][16] = x[t] . a[l_t] ----------------
// block = 4 consecutive tokens; aT reads fully coalesced (lane-stride 16B)
__global__ __launch_bounds__(256) void fused_x_kernel(const float* __restrict__ x,
                                                      const float* __restrict__ aT,
                                                      const int* __restrict__ indices,
                                                      unsigned short* __restrict__ Xb,
                                                      float* __restrict__ u) {
  const int t0 = blockIdx.x * 4;
  const int tid = threadIdx.x;
  const int l = lora_of(indices, t0);
  const float* __restrict__ aTl = aT + (size_t)l * H_DIM * R_DIM;

  float acc[4][16];
#pragma unroll
  for (int t = 0; t < 4; ++t)
#pragma unroll
    for (int r = 0; r < 16; ++r) acc[t][r] = 0.f;

#pragma unroll
  for (int c = 0; c < 4; ++c) {
    const int h = c * 1024 + tid * 4;
    union { float4 v; float f[4]; } xv[4];
#pragma unroll
    for (int t = 0; t < 4; ++t)
      xv[t].v = *(const float4*)(x + (size_t)(t0 + t) * H_DIM + h);
#pragma unroll
    for (int t = 0; t < 4; ++t) {
      ushort4_t o;
      o.x = f2bf(xv[t].f[0]); o.y = f2bf(xv[t].f[1]);
      o.z = f2bf(xv[t].f[2]); o.w = f2bf(xv[t].f[3]);
      *(ushort4_t*)(Xb + (size_t)(t0 + t) * H_DIM + h) = o;
    }
#pragma unroll
    for (int r = 0; r < 16; ++r) {
      float4 av = *(const float4*)(aTl + (size_t)r * H_DIM + h);
#pragma unroll
      for (int t = 0; t < 4; ++t)
        acc[t][r] += xv[t].f[0] * av.x + xv[t].f[1] * av.y +
                     xv[t].f[2] * av.z + xv[t].f[3] * av.w;
    }
  }

#pragma unroll
  for (int t = 0; t < 4; ++t)
#pragma unroll
    for (int r = 0; r < 16; ++r)
#pragma unroll
      for (int off = 32; off > 0; off >>= 1)
        acc[t][r] += __shfl_xor(acc[t][r], off, 64);

  __shared__ float red[4][64];
  const int lane = tid & 63, wv = tid >> 6;
  if (lane == 0) {
#pragma unroll
    for (int t = 0; t < 4; ++t)
#pragma unroll
      for (int r = 0; r < 16; ++r) red[wv][t * 16 + r] = acc[t][r];
  }
  __syncthreads();
  if (tid < 64) {
    float s = red[0][tid] + red[1][tid] + red[2][tid] + red[3][tid];
    u[(size_t)t0 * 16 + tid] = s;
  }
}

// ---------------- bf16 MFMA GEMM 256x256, BK=64, counted-vmcnt pipeline ----------------
// 8 waves (2Mx4N), per-wave out 128x64 (8m x 4n fragments), LDS 128KB dynamic:
// A[2][256][64] + B[2][256][64] bf16, swizzle byte^=((byte>>9)&1)<<5 (both sides).
// Schedule per K-tile: {4 phases: ds_read+MFMA} barrier; stage t+2 into freed buf;
// vmcnt(8) (tile t+1 landed, 8 loads of t+2 in flight); barrier. Never drains in loop.
__global__ __launch_bounds__(512) void gemm256(const unsigned short* __restrict__ A,
                                               const unsigned short* __restrict__ B,
                                               const float* __restrict__ bias,
                                               const float* __restrict__ lora_b,
                                               const int* __restrict__ indices,
                                               const float* __restrict__ u,
                                               float* __restrict__ out) {
  extern __shared__ unsigned short lds[];  // 65536 shorts = 128KB
  const int tid = threadIdx.x;
  const int lane = tid & 63;
  const int wid = tid >> 6;
  const int wr = wid >> 2;  // 0..1
  const int wc = wid & 3;   // 0..3
  const int row0 = blockIdx.y * 256;
  const int col0 = blockIdx.x * 256;

  f32x4_t acc[8][4];
#pragma unroll
  for (int m = 0; m < 8; ++m)
#pragma unroll
    for (int n = 0; n < 4; ++n) acc[m][n] = (f32x4_t){0.f, 0.f, 0.f, 0.f};

  // --- staging addresses ---
  // dest (linear, per round rd): elem = rd*4096 + tid*8  (wave-uniform + lane*16B)
  // the 16B chunk landing at D must be logical S(D): row = D>>7 (unchanged),
  // kbyte = (D&127) ^ (bit9(D)<<5); bit9(D) = row bit2 = (tid>>5)&1
  const int srow = tid >> 3;
  const int kbyte = ((tid & 7) * 16) ^ (((tid >> 5) & 1) << 5);
  const unsigned short* aS0 = A + (size_t)(row0 + 0 * 64 + srow) * H_DIM + (kbyte >> 1);
  const unsigned short* aS1 = A + (size_t)(row0 + 1 * 64 + srow) * H_DIM + (kbyte >> 1);
  const unsigned short* aS2 = A + (size_t)(row0 + 2 * 64 + srow) * H_DIM + (kbyte >> 1);
  const unsigned short* aS3 = A + (size_t)(row0 + 3 * 64 + srow) * H_DIM + (kbyte >> 1);
  const unsigned short* bS0 = B + (size_t)(col0 + 0 * 64 + srow) * H_DIM + (kbyte >> 1);
  const unsigned short* bS1 = B + (size_t)(col0 + 1 * 64 + srow) * H_DIM + (kbyte >> 1);
  const unsigned short* bS2 = B + (size_t)(col0 + 2 * 64 + srow) * H_DIM + (kbyte >> 1);
  const unsigned short* bS3 = B + (size_t)(col0 + 3 * 64 + srow) * H_DIM + (kbyte >> 1);

#define STAGE(kt, d) do {                                                  \
    unsigned short* La_ = lds + (d) * 16384;                               \
    unsigned short* Lb_ = lds + 32768 + (d) * 16384;                       \
    gload16(aS0 + (kt), La_ + tid * 8);                                    \
    gload16(aS1 + (kt), La_ + 4096 + tid * 8);                             \
    gload16(aS2 + (kt), La_ + 8192 + tid * 8);                             \
    gload16(aS3 + (kt), La_ + 12288 + tid * 8);                            \
    gload16(bS0 + (kt), Lb_ + tid * 8);                                    \
    gload16(bS1 + (kt), Lb_ + 4096 + tid * 8);                             \
    gload16(bS2 + (kt), Lb_ + 8192 + tid * 8);                             \
    gload16(bS3 + (kt), Lb_ + 12288 + tid * 8);                            \
  } while (0)

  // --- fragment read offsets (swizzled) ---
  // logical: row, kbyte kb = kk*64 + (lane>>4)*16; read addr byte = row*128 + (kb ^ ((row&4)<<3))
  const int rA = wr * 128 + (lane & 15);
  const int rB = wc * 64 + (lane & 15);
  const int aBase = rA * 64;  // elems
  const int bBase = rB * 64;
  const int ks0 = ((((lane >> 4) * 16)) ^ ((lane & 4) << 3)) >> 1;        // kk=0, elems
  const int ks1 = (((64 + (lane >> 4) * 16)) ^ ((lane & 4) << 3)) >> 1;   // kk=1, elems

  // --- prologue: stage tiles 0,1; wait tile 0 (oldest 8 loads) ---
  STAGE(0, 0);
  STAGE(64, 1);
  VMCNT8();
  SBAR();

#pragma unroll 2
  for (int t = 0; t < H_DIM / 64; ++t) {
    const int cur = t & 1;
    const unsigned short* La = lds + cur * 16384;
    const unsigned short* Lb = lds + 32768 + cur * 16384;

    bf16x8_t b0, b1, b2, b3, a0, a1, a2, a3;
    // ---- phase 0: B kk0 + A m0-3 kk0 ----
    b0 = *(const bf16x8_t*)(Lb + bBase + 0 * 1024 + ks0);
    b1 = *(const bf16x8_t*)(Lb + bBase + 1 * 1024 + ks0);
    b2 = *(const bf16x8_t*)(Lb + bBase + 2 * 1024 + ks0);
    b3 = *(const bf16x8_t*)(Lb + bBase + 3 * 1024 + ks0);
    a0 = *(const bf16x8_t*)(La + aBase + 0 * 1024 + ks0);
    a1 = *(const bf16x8_t*)(La + aBase + 1 * 1024 + ks0);
    a2 = *(const bf16x8_t*)(La + aBase + 2 * 1024 + ks0);
    a3 = *(const bf16x8_t*)(La + aBase + 3 * 1024 + ks0);
    __builtin_amdgcn_s_setprio(1);
    acc[0][0] = __builtin_amdgcn_mfma_f32_16x16x32_bf16(a0, b0, acc[0][0], 0, 0, 0);
    acc[0][1] = __builtin_amdgcn_mfma_f32_16x16x32_bf16(a0, b1, acc[0][1], 0, 0, 0);
    acc[0][2] = __builtin_amdgcn_mfma_f32_16x16x32_bf16(a0, b2, acc[0][2], 0, 0, 0);
    acc[0][3] = __builtin_amdgcn_mfma_f32_16x16x32_bf16(a0, b3, acc[0][3], 0, 0, 0);
    acc[1][0] = __builtin_amdgcn_mfma_f32_16x16x32_bf16(a1, b0, acc[1][0], 0, 0, 0);
    acc[1][1] = __builtin_amdgcn_mfma_f32_16x16x32_bf16(a1, b1, acc[1][1], 0, 0, 0);
    acc[1][2] = __builtin_amdgcn_mfma_f32_16x16x32_bf16(a1, b2, acc[1][2], 0, 0, 0);
    acc[1][3] = __builtin_amdgcn_mfma_f32_16x16x32_bf16(a1, b3, acc[1][3], 0, 0, 0);
    acc[2][0] = __builtin_amdgcn_mfma_f32_16x16x32_bf16(a2, b0, acc[2][0], 0, 0, 0);
    acc[2][1] = __builtin_amdgcn_mfma_f32_16x16x32_bf16(a2, b1, acc[2][1], 0, 0, 0);
    acc[2][2] = __builtin_amdgcn_mfma_f32_16x16x32_bf16(a2, b2, acc[2][2], 0, 0, 0);
    acc[2][3] = __builtin_amdgcn_mfma_f32_16x16x32_bf16(a2, b3, acc[2][3], 0, 0, 0);
    acc[3][0] = __builtin_amdgcn_mfma_f32_16x16x32_bf16(a3, b0, acc[3][0], 0, 0, 0);
    acc[3][1] = __builtin_amdgcn_mfma_f32_16x16x32_bf16(a3, b1, acc[3][1], 0, 0, 0);
    acc[3][2] = __builtin_amdgcn_mfma_f32_16x16x32_bf16(a3, b2, acc[3][2], 0, 0, 0);
    acc[3][3] = __builtin_amdgcn_mfma_f32_16x16x32_bf16(a3, b3, acc[3][3], 0, 0, 0);
    __builtin_amdgcn_s_setprio(0);

    // ---- phase 1: B kk1 + A m0-3 kk1 ----
    bf16x8_t c0, c1, c2, c3;
    c0 = *(const bf16x8_t*)(Lb + bBase + 0 * 1024 + ks1);
    c1 = *(const bf16x8_t*)(Lb + bBase + 1 * 1024 + ks1);
    c2 = *(const bf16x8_t*)(Lb + bBase + 2 * 1024 + ks1);
    c3 = *(const bf16x8_t*)(Lb + bBase + 3 * 1024 + ks1);
    a0 = *(const bf16x8_t*)(La + aBase + 0 * 1024 + ks1);
    a1 = *(const bf16x8_t*)(La + aBase + 1 * 1024 + ks1);
    a2 = *(const bf16x8_t*)(La + aBase + 2 * 1024 + ks1);
    a3 = *(const bf16x8_t*)(La + aBase + 3 * 1024 + ks1);
    __builtin_amdgcn_s_setprio(1);
    acc[0][0] = __builtin_amdgcn_mfma_f32_16x16x32_bf16(a0, c0, acc[0][0], 0, 0, 0);
    acc[0][1] = __builtin_amdgcn_mfma_f32_16x16x32_bf16(a0, c1, acc[0][1], 0, 0, 0);
    acc[0][2] = __builtin_amdgcn_mfma_f32_16x16x32_bf16(a0, c2, acc[0][2], 0, 0, 0);
    acc[0][3] = __builtin_amdgcn_mfma_f32_16x16x32_bf16(a0, c3, acc[0][3], 0, 0, 0);
    acc[1][0] = __builtin_amdgcn_mfma_f32_16x16x32_bf16(a1, c0, acc[1][0], 0, 0, 0);
    acc[1][1] = __builtin_amdgcn_mfma_f32_16x16x32_bf16(a1, c1, acc[1][1], 0, 0, 0);
    acc[1][2] = __builtin_amdgcn_mfma_f32_16x16x32_bf16(a1, c2, acc[1][2], 0, 0, 0);
    acc[1][3] = __builtin_amdgcn_mfma_f32_16x16x32_bf16(a1, c3, acc[1][3], 0, 0, 0);
    acc[2][0] = __builtin_amdgcn_mfma_f32_16x16x32_bf16(a2, c0, acc[2][0], 0, 0, 0);
    acc[2][1] = __builtin_amdgcn_mfma_f32_16x16x32_bf16(a2, c1, acc[2][1], 0, 0, 0);
    acc[2][2] = __builtin_amdgcn_mfma_f32_16x16x32_bf16(a2, c2, acc[2][2], 0, 0, 0);
    acc[2][3] = __builtin_amdgcn_mfma_f32_16x16x32_bf16(a2, c3, acc[2][3], 0, 0, 0);
    acc[3][0] = __builtin_amdgcn_mfma_f32_16x16x32_bf16(a3, c0, acc[3][0], 0, 0, 0);
    acc[3][1] = __builtin_amdgcn_mfma_f32_16x16x32_bf16(a3, c1, acc[3][1], 0, 0, 0);
    acc[3][2] = __builtin_amdgcn_mfma_f32_16x16x32_bf16(a3, c2, acc[3][2], 0, 0, 0);
    acc[3][3] = __builtin_amdgcn_mfma_f32_16x16x32_bf16(a3, c3, acc[3][3], 0, 0, 0);
    __builtin_amdgcn_s_setprio(0);

    // ---- phase 2: A m4-7 kk0 ----
    a0 = *(const bf16x8_t*)(La + aBase + 4 * 1024 + ks0);
    a1 = *(const bf16x8_t*)(La + aBase + 5 * 1024 + ks0);
    a2 = *(const bf16x8_t*)(La + aBase + 6 * 1024 + ks0);
    a3 = *(const bf16x8_t*)(La + aBase + 7 * 1024 + ks0);
    __builtin_amdgcn_s_setprio(1);
    acc[4][0] = __builtin_amdgcn_mfma_f32_16x16x32_bf16(a0, b0, acc[4][0], 0, 0, 0);
    acc[4][1] = __builtin_amdgcn_mfma_f32_16x16x32_bf16(a0, b1, acc[4][1], 0, 0, 0);
    acc[4][2] = __builtin_amdgcn_mfma_f32_16x16x32_bf16(a0, b2, acc[4][2], 0, 0, 0);
    acc[4][3] = __builtin_amdgcn_mfma_f32_16x16x32_bf16(a0, b3, acc[4][3], 0, 0, 0);
    acc[5][0] = __builtin_amdgcn_mfma_f32_16x16x32_bf16(a1, b0, acc[5][0], 0, 0, 0);
    acc[5][1] = __builtin_amdgcn_mfma_f32_16x16x32_bf16(a1, b1, acc[5][1], 0, 0, 0);
    acc[5][2] = __builtin_amdgcn_mfma_f32_16x16x32_bf16(a1, b2, acc[5][2], 0, 0, 0);
    acc[5][3] = __builtin_amdgcn_mfma_f32_16x16x32_bf16(a1, b3, acc[5][3], 0, 0, 0);
    acc[6][0] = __builtin_amdgcn_mfma_f32_16x16x32_bf16(a2, b0, acc[6][0], 0, 0, 0);
    acc[6][1] = __builtin_amdgcn_mfma_f32_16x16x32_bf16(a2, b1, acc[6][1], 0, 0, 0);
    acc[6][2] = __builtin_amdgcn_mfma_f32_16x16x32_bf16(a2, b2, acc[6][2], 0, 0, 0);
    acc[6][3] = __builtin_amdgcn_mfma_f32_16x16x32_bf16(a2, b3, acc[6][3], 0, 0, 0);
    acc[7][0] = __builtin_amdgcn_mfma_f32_16x16x32_bf16(a3, b0, acc[7][0], 0, 0, 0);
    acc[7][1] = __builtin_amdgcn_mfma_f32_16x16x32_bf16(a3, b1, acc[7][1], 0, 0, 0);
    acc[7][2] = __builtin_amdgcn_mfma_f32_16x16x32_bf16(a3, b2, acc[7][2], 0, 0, 0);
    acc[7][3] = __builtin_amdgcn_mfma_f32_16x16x32_bf16(a3, b3, acc[7][3], 0, 0, 0);
    __builtin_amdgcn_s_setprio(0);

    // ---- phase 3: A m4-7 kk1 ----
    a0 = *(const bf16x8_t*)(La + aBase + 4 * 1024 + ks1);
    a1 = *(const bf16x8_t*)(La + aBase + 5 * 1024 + ks1);
    a2 = *(const bf16x8_t*)(La + aBase + 6 * 1024 + ks1);
    a3 = *(const bf16x8_t*)(La + aBase + 7 * 1024 + ks1);
    __builtin_amdgcn_s_setprio(1);
    acc[4][0] = __builtin_amdgcn_mfma_f32_16x16x32_bf16(a0, c0, acc[4][0], 0, 0, 0);
    acc[4][1] = __builtin_amdgcn_mfma_f32_16x16x32_bf16(a0, c1, acc[4][1], 0, 0, 0);
    acc[4][2] = __builtin_amdgcn_mfma_f32_16x16x32_bf16(a0, c2, acc[4][2], 0, 0, 0);
    acc[4][3] = __builtin_amdgcn_mfma_f32_16x16x32_bf16(a0, c3, acc[4][3], 0, 0, 0);
    acc[5][0] = __builtin_amdgcn_mfma_f32_16x16x32_bf16(a1, c0, acc[5][0], 0, 0, 0);
    acc[5][1] = __builtin_amdgcn_mfma_f32_16x16x32_bf16(a1, c1, acc[5][1], 0, 0, 0);
    acc[5][2] = __builtin_amdgcn_mfma_f32_16x16x32_bf16(a1, c2, acc[5][2], 0, 0, 0);
    acc[5][3] = __builtin_amdgcn_mfma_f32_16x16x32_bf16(a1, c3, acc[5][3], 0, 0, 0);
    acc[6][0] = __builtin_amdgcn_mfma_f32_16x16x32_bf16(a2, c0, acc[6][0], 0, 0, 0);
    acc[6][1] = __builtin_amdgcn_mfma_f32_16x16x32_bf16(a2, c1, acc[6][1], 0, 0, 0);
    acc[6][2] = __builtin_amdgcn_mfma_f32_16x16x32_bf16(a2, c2, acc[6][2], 0, 0, 0);
    acc[6][3] = __builtin_amdgcn_mfma_f32_16x16x32_bf16(a2, c3, acc[6][3], 0, 0, 0);
    acc[7][0] = __builtin_amdgcn_mfma_f32_16x16x32_bf16(a3, c0, acc[7][0], 0, 0, 0);
    acc[7][1] = __builtin_amdgcn_mfma_f32_16x16x32_bf16(a3, c1, acc[7][1], 0, 0, 0);
    acc[7][2] = __builtin_amdgcn_mfma_f32_16x16x32_bf16(a3, c2, acc[7][2], 0, 0, 0);
    acc[7][3] = __builtin_amdgcn_mfma_f32_16x16x32_bf16(a3, c3, acc[7][3], 0, 0, 0);
    __builtin_amdgcn_s_setprio(0);

    SBAR();  // all waves done reading buf[cur]
    if (t + 2 < H_DIM / 64) {
      STAGE((t + 2) * 64, cur);  // overwrite freed buffer
      VMCNT8();                  // tile t+1 fully landed; t+2's 8 in flight
    } else {
      VMCNT0();                  // tail: drain
    }
    SBAR();  // all waves certified their slices
  }
#undef STAGE

  // ---- fused LoRA-B epilogue: acc += u[row] . lora_b[l][:, col] ----
  const int l = lora_of(indices, row0);
  float* uL = (float*)lds;         // [256][16] f32, 16KB
  float* bL = (float*)lds + 4096;  // [16][256] f32, 16KB
  {
    const float* ug = u + (size_t)row0 * 16;
    *(float4*)(uL + tid * 8) = *(const float4*)(ug + tid * 8);
    *(float4*)(uL + tid * 8 + 4) = *(const float4*)(ug + tid * 8 + 4);
    int br = tid >> 5, bc = (tid & 31) * 8;
    const float* bg = lora_b + ((size_t)l * R_DIM + br) * O_DIM + col0 + bc;
    *(float4*)(bL + br * 256 + bc) = *(const float4*)bg;
    *(float4*)(bL + br * 256 + bc + 4) = *(const float4*)(bg + 4);
  }
  SBAR();

  const int cl0 = wc * 64 + (lane & 15);
  const int rl0 = wr * 128 + (lane >> 4) * 4;
#pragma unroll
  for (int r = 0; r < 16; ++r) {
    float b0 = bL[r * 256 + cl0];
    float b1 = bL[r * 256 + cl0 + 16];
    float b2 = bL[r * 256 + cl0 + 32];
    float b3 = bL[r * 256 + cl0 + 48];
#pragma unroll
    for (int m = 0; m < 8; ++m)
#pragma unroll
      for (int q = 0; q < 4; ++q) {
        float uv = uL[(rl0 + m * 16 + q) * 16 + r];
        acc[m][0][q] += uv * b0;
        acc[m][1][q] += uv * b1;
        acc[m][2][q] += uv * b2;
        acc[m][3][q] += uv * b3;
      }
  }

  float bv[4];
#pragma unroll
  for (int n = 0; n < 4; ++n) bv[n] = bias[col0 + cl0 + n * 16];
#pragma unroll
  for (int m = 0; m < 8; ++m)
#pragma unroll
    for (int n = 0; n < 4; ++n)
#pragma unroll
      for (int q = 0; q < 4; ++q) {
        int row = row0 + rl0 + m * 16 + q;
        out[(size_t)row * O_DIM + (col0 + cl0 + n * 16)] = acc[m][n][q] + bv[n];
      }
}

extern "C" void kernel_launch(void* const* d_in, const int* in_sizes, int n_in,
                              void* d_out, int out_size, void* d_ws, size_t ws_size,
                              hipStream_t stream) {
  const float* x      = (const float*)d_in[0];
  const float* weight = (const float*)d_in[1];
  const float* bias   = (const float*)d_in[2];
  const float* lora_a = (const float*)d_in[3];
  const float* lora_b = (const float*)d_in[4];
  const int*   indices = (const int*)d_in[5];
  float* out = (float*)d_out;

  // workspace: [Xb 32MB][Wb 32MB][u 256KB]; aT aliases Wb (consumed before cvt_W)
  unsigned short* Xb = (unsigned short*)d_ws;
  unsigned short* Wb = Xb + (size_t)T_DIM * H_DIM;
  float* u = (float*)(Wb + (size_t)O_DIM * H_DIM);
  float* aT = (float*)Wb;  // transient alias

  hipFuncSetAttribute((const void*)gemm256,
                      hipFuncAttributeMaxDynamicSharedMemorySize, 131072);

  const int nX = T_DIM * H_DIM;
  transpose_a<<<dim3(16, 8), 256, 0, stream>>>(lora_a, aT);
  fused_x_kernel<<<T_DIM / 4, 256, 0, stream>>>(x, aT, indices, Xb, u);
  cvt_kernel<<<nX / 8 / 256, 256, 0, stream>>>(weight, Wb, nX);
  gemm256<<<dim3(O_DIM / 256, T_DIM / 256), 512, 131072, stream>>>(
      Xb, Wb, bias, lora_b, indices, u, out);
}

// Round 7
// 339.883 us; speedup vs baseline: 1.3378x; 1.0641x over previous
//
#include <hip/hip_runtime.h>
#include <hip/hip_bf16.h>
#include <stdint.h>

#define T_DIM 4096
#define H_DIM 4096
#define O_DIM 4096
#define R_DIM 16
#define S_SEG 8

typedef __attribute__((ext_vector_type(8))) short bf16x8_t;  // 8 bf16 in 4 VGPRs
typedef __attribute__((ext_vector_type(4))) float f32x4_t;

// round-to-nearest-even f32 -> bf16
__device__ __forceinline__ unsigned short f2bf(float f) {
  union { float f; unsigned int u; } v; v.f = f;
  unsigned int u = v.u;
  unsigned int r = (u + 0x7fffu + ((u >> 16) & 1u)) >> 16;
  return (unsigned short)r;
}

__device__ __forceinline__ void gload16(const void* g, void* l) {
  __builtin_amdgcn_global_load_lds(
      (const __attribute__((address_space(1))) unsigned int*)g,
      (__attribute__((address_space(3))) unsigned int*)l,
      16, 0, 0);
}

// segment lookup: searchsorted(starts, t, 'right') - 1; starts at indices[2s]
__device__ __forceinline__ int lora_of(const int* __restrict__ indices, int t) {
  int seg = 0;
#pragma unroll
  for (int s = 1; s < S_SEG; ++s)
    if (indices[2 * s] <= t) seg = s;
  return indices[2 * seg + 1];
}

#define SBAR() do { asm volatile("" ::: "memory"); __builtin_amdgcn_s_barrier(); asm volatile("" ::: "memory"); } while (0)
#define VMCNT8() asm volatile("s_waitcnt vmcnt(8)" ::: "memory")
#define VMCNT0() asm volatile("s_waitcnt vmcnt(0)" ::: "memory")

// ---------------- kernel 1: cvt x->Xb (bf16)  +  transpose/cvt lora_a -> aTb ----------------
// blocks [0,128): aTb[l][r][h] = bf16(a[l][h][r]);  blocks [128, 128+8192): cvt x
__global__ __launch_bounds__(256) void prep1_kernel(const float* __restrict__ x,
                                                    const float* __restrict__ a,
                                                    unsigned short* __restrict__ Xb,
                                                    unsigned short* __restrict__ aTb) {
  const int bid = blockIdx.x;
  const int tid = threadIdx.x;
  if (bid < 128) {
    // transpose: l = bid>>4, h-tile = (bid&15)*256
    __shared__ float tile[16][257];  // [r][h-local]
    const int l = bid >> 4, h0 = (bid & 15) * 256;
    const float* al = a + ((size_t)l * H_DIM + h0) * R_DIM;
    for (int i = tid; i < 4096; i += 256)
      tile[i & 15][i >> 4] = al[i];  // i = h_local*16 + r
    __syncthreads();
    const int r = tid >> 4, hh = (tid & 15) * 16;
    unsigned short* o = aTb + ((size_t)l * R_DIM + r) * H_DIM + h0 + hh;
#pragma unroll
    for (int j = 0; j < 16; ++j) o[j] = f2bf(tile[r][hh + j]);
  } else {
    const int i = (bid - 128) * 2048 + tid * 8;
    float4 p = *(const float4*)(x + i);
    float4 q = *(const float4*)(x + i + 4);
    union { unsigned short s[8]; bf16x8_t v; } rr;
    rr.s[0] = f2bf(p.x); rr.s[1] = f2bf(p.y); rr.s[2] = f2bf(p.z); rr.s[3] = f2bf(p.w);
    rr.s[4] = f2bf(q.x); rr.s[5] = f2bf(q.y); rr.s[6] = f2bf(q.z); rr.s[7] = f2bf(q.w);
    *(bf16x8_t*)(Xb + i) = rr.v;
  }
}

// ---------------- kernel 2: u = Xb . aTb[l]^T (MFMA)  +  cvt weight->Wb ----------------
// blocks [0,32): u_gemm, 128 tokens/block, 4 waves x 32 tokens; blocks [32, 32+8192): cvt W
__global__ __launch_bounds__(256) void prep2_kernel(const float* __restrict__ weight,
                                                    const unsigned short* __restrict__ Xb,
                                                    const unsigned short* __restrict__ aTb,
                                                    const int* __restrict__ indices,
                                                    unsigned short* __restrict__ Wb,
                                                    float* __restrict__ u) {
  const int bid = blockIdx.x;
  const int tid = threadIdx.x;
  if (bid < 32) {
    const int t0 = bid * 128;                 // 128 | 512 -> single segment
    const int l = lora_of(indices, t0);
    const int lane = tid & 63, wv = tid >> 6;
    const int trow = t0 + wv * 32;
    const unsigned short* Arow = Xb + (size_t)(trow + (lane & 15)) * H_DIM + (lane >> 4) * 8;
    const unsigned short* Brow = aTb + ((size_t)l * R_DIM + (lane & 15)) * H_DIM + (lane >> 4) * 8;
    f32x4_t acc0 = (f32x4_t){0.f, 0.f, 0.f, 0.f};
    f32x4_t acc1 = (f32x4_t){0.f, 0.f, 0.f, 0.f};
#pragma unroll 4
    for (int k = 0; k < H_DIM; k += 32) {
      bf16x8_t af0 = *(const bf16x8_t*)(Arow + k);
      bf16x8_t af1 = *(const bf16x8_t*)(Arow + (size_t)16 * H_DIM + k);
      bf16x8_t bfr = *(const bf16x8_t*)(Brow + k);
      acc0 = __builtin_amdgcn_mfma_f32_16x16x32_bf16(af0, bfr, acc0, 0, 0, 0);
      acc1 = __builtin_amdgcn_mfma_f32_16x16x32_bf16(af1, bfr, acc1, 0, 0, 0);
    }
    // C/D: col = lane&15 (rank), row = (lane>>4)*4 + q
    const int c = lane & 15, g4 = (lane >> 4) * 4;
#pragma unroll
    for (int q = 0; q < 4; ++q) {
      u[(size_t)(trow + g4 + q) * 16 + c] = acc0[q];
      u[(size_t)(trow + 16 + g4 + q) * 16 + c] = acc1[q];
    }
  } else {
    const int i = (bid - 32) * 2048 + tid * 8;
    float4 p = *(const float4*)(weight + i);
    float4 q = *(const float4*)(weight + i + 4);
    union { unsigned short s[8]; bf16x8_t v; } rr;
    rr.s[0] = f2bf(p.x); rr.s[1] = f2bf(p.y); rr.s[2] = f2bf(p.z); rr.s[3] = f2bf(p.w);
    rr.s[4] = f2bf(q.x); rr.s[5] = f2bf(q.y); rr.s[6] = f2bf(q.z); rr.s[7] = f2bf(q.w);
    *(bf16x8_t*)(Wb + i) = rr.v;
  }
}

// ---------------- bf16 MFMA GEMM 256x256, BK=64, counted-vmcnt pipeline ----------------
// 8 waves (2Mx4N), per-wave out 128x64 (8m x 4n frags), LDS 128KB dynamic:
// A[2][256][64] + B[2][256][64] bf16. Full 3-bit swizzle (both sides, rule #21):
//   physical byte = row*128 + (kbyte ^ ((row&7)<<4))   [involution, bits 4-6]
// -> each 16-lane frag-read group covers all 8 16B-chunks of a row-span: 32-bank uniform.
__global__ __launch_bounds__(512) void gemm256(const unsigned short* __restrict__ A,
                                               const unsigned short* __restrict__ B,
                                               const float* __restrict__ bias,
                                               const float* __restrict__ lora_b,
                                               const int* __restrict__ indices,
                                               const float* __restrict__ u,
                                               float* __restrict__ out) {
  extern __shared__ unsigned short lds[];  // 65536 shorts = 128KB
  const int tid = threadIdx.x;
  const int lane = tid & 63;
  const int wid = tid >> 6;
  const int wr = wid >> 2;  // 0..1
  const int wc = wid & 3;   // 0..3
  const int row0 = blockIdx.y * 256;
  const int col0 = blockIdx.x * 256;

  f32x4_t acc[8][4];
#pragma unroll
  for (int m = 0; m < 8; ++m)
#pragma unroll
    for (int n = 0; n < 4; ++n) acc[m][n] = (f32x4_t){0.f, 0.f, 0.f, 0.f};

  // --- staging: dest linear elem = seg*4096 + tid*8 -> row = seg*64 + (tid>>3) ---
  // source must hold logical kbyte = ((tid&7)*16) ^ ((row&7)<<4), row&7 = (tid>>3)&7
  const int srow = tid >> 3;
  const int kbyte = ((tid & 7) * 16) ^ (((tid >> 3) & 7) << 4);
  const unsigned short* aS0 = A + (size_t)(row0 + 0 * 64 + srow) * H_DIM + (kbyte >> 1);
  const unsigned short* aS1 = A + (size_t)(row0 + 1 * 64 + srow) * H_DIM + (kbyte >> 1);
  const unsigned short* aS2 = A + (size_t)(row0 + 2 * 64 + srow) * H_DIM + (kbyte >> 1);
  const unsigned short* aS3 = A + (size_t)(row0 + 3 * 64 + srow) * H_DIM + (kbyte >> 1);
  const unsigned short* bS0 = B + (size_t)(col0 + 0 * 64 + srow) * H_DIM + (kbyte >> 1);
  const unsigned short* bS1 = B + (size_t)(col0 + 1 * 64 + srow) * H_DIM + (kbyte >> 1);
  const unsigned short* bS2 = B + (size_t)(col0 + 2 * 64 + srow) * H_DIM + (kbyte >> 1);
  const unsigned short* bS3 = B + (size_t)(col0 + 3 * 64 + srow) * H_DIM + (kbyte >> 1);

#define STAGE(kt, d) do {                                                  \
    unsigned short* La_ = lds + (d) * 16384;                               \
    unsigned short* Lb_ = lds + 32768 + (d) * 16384;                       \
    gload16(aS0 + (kt), La_ + tid * 8);                                    \
    gload16(aS1 + (kt), La_ + 4096 + tid * 8);                             \
    gload16(aS2 + (kt), La_ + 8192 + tid * 8);                             \
    gload16(aS3 + (kt), La_ + 12288 + tid * 8);                            \
    gload16(bS0 + (kt), Lb_ + tid * 8);                                    \
    gload16(bS1 + (kt), Lb_ + 4096 + tid * 8);                             \
    gload16(bS2 + (kt), Lb_ + 8192 + tid * 8);                             \
    gload16(bS3 + (kt), Lb_ + 12288 + tid * 8);                            \
  } while (0)

  // --- fragment reads: logical kbyte kb = kk*64 + (lane>>4)*16; row&7 = lane&7 ---
  const int rA = wr * 128 + (lane & 15);
  const int rB = wc * 64 + (lane & 15);
  const int aBase = rA * 64;  // elems
  const int bBase = rB * 64;
  const int swz = (lane & 7) << 4;                         // byte bits 4-6
  const int ks0 = (((lane >> 4) * 16) ^ swz) >> 1;         // kk=0, elems
  const int ks1 = ((64 + (lane >> 4) * 16) ^ swz) >> 1;    // kk=1, elems

  // --- prologue: stage tiles 0,1; wait tile 0 (oldest 8 loads) ---
  STAGE(0, 0);
  STAGE(64, 1);
  VMCNT8();
  SBAR();

#pragma unroll 2
  for (int t = 0; t < H_DIM / 64; ++t) {
    const int cur = t & 1;
    const unsigned short* La = lds + cur * 16384;
    const unsigned short* Lb = lds + 32768 + cur * 16384;

    bf16x8_t b0, b1, b2, b3, a0, a1, a2, a3;
    // ---- phase 0: B kk0 + A m0-3 kk0 ----
    b0 = *(const bf16x8_t*)(Lb + bBase + 0 * 1024 + ks0);
    b1 = *(const bf16x8_t*)(Lb + bBase + 1 * 1024 + ks0);
    b2 = *(const bf16x8_t*)(Lb + bBase + 2 * 1024 + ks0);
    b3 = *(const bf16x8_t*)(Lb + bBase + 3 * 1024 + ks0);
    a0 = *(const bf16x8_t*)(La + aBase + 0 * 1024 + ks0);
    a1 = *(const bf16x8_t*)(La + aBase + 1 * 1024 + ks0);
    a2 = *(const bf16x8_t*)(La + aBase + 2 * 1024 + ks0);
    a3 = *(const bf16x8_t*)(La + aBase + 3 * 1024 + ks0);
    __builtin_amdgcn_s_setprio(1);
    acc[0][0] = __builtin_amdgcn_mfma_f32_16x16x32_bf16(a0, b0, acc[0][0], 0, 0, 0);
    acc[0][1] = __builtin_amdgcn_mfma_f32_16x16x32_bf16(a0, b1, acc[0][1], 0, 0, 0);
    acc[0][2] = __builtin_amdgcn_mfma_f32_16x16x32_bf16(a0, b2, acc[0][2], 0, 0, 0);
    acc[0][3] = __builtin_amdgcn_mfma_f32_16x16x32_bf16(a0, b3, acc[0][3], 0, 0, 0);
    acc[1][0] = __builtin_amdgcn_mfma_f32_16x16x32_bf16(a1, b0, acc[1][0], 0, 0, 0);
    acc[1][1] = __builtin_amdgcn_mfma_f32_16x16x32_bf16(a1, b1, acc[1][1], 0, 0, 0);
    acc[1][2] = __builtin_amdgcn_mfma_f32_16x16x32_bf16(a1, b2, acc[1][2], 0, 0, 0);
    acc[1][3] = __builtin_amdgcn_mfma_f32_16x16x32_bf16(a1, b3, acc[1][3], 0, 0, 0);
    acc[2][0] = __builtin_amdgcn_mfma_f32_16x16x32_bf16(a2, b0, acc[2][0], 0, 0, 0);
    acc[2][1] = __builtin_amdgcn_mfma_f32_16x16x32_bf16(a2, b1, acc[2][1], 0, 0, 0);
    acc[2][2] = __builtin_amdgcn_mfma_f32_16x16x32_bf16(a2, b2, acc[2][2], 0, 0, 0);
    acc[2][3] = __builtin_amdgcn_mfma_f32_16x16x32_bf16(a2, b3, acc[2][3], 0, 0, 0);
    acc[3][0] = __builtin_amdgcn_mfma_f32_16x16x32_bf16(a3, b0, acc[3][0], 0, 0, 0);
    acc[3][1] = __builtin_amdgcn_mfma_f32_16x16x32_bf16(a3, b1, acc[3][1], 0, 0, 0);
    acc[3][2] = __builtin_amdgcn_mfma_f32_16x16x32_bf16(a3, b2, acc[3][2], 0, 0, 0);
    acc[3][3] = __builtin_amdgcn_mfma_f32_16x16x32_bf16(a3, b3, acc[3][3], 0, 0, 0);
    __builtin_amdgcn_s_setprio(0);

    // ---- phase 1: B kk1 + A m0-3 kk1 ----
    bf16x8_t c0, c1, c2, c3;
    c0 = *(const bf16x8_t*)(Lb + bBase + 0 * 1024 + ks1);
    c1 = *(const bf16x8_t*)(Lb + bBase + 1 * 1024 + ks1);
    c2 = *(const bf16x8_t*)(Lb + bBase + 2 * 1024 + ks1);
    c3 = *(const bf16x8_t*)(Lb + bBase + 3 * 1024 + ks1);
    a0 = *(const bf16x8_t*)(La + aBase + 0 * 1024 + ks1);
    a1 = *(const bf16x8_t*)(La + aBase + 1 * 1024 + ks1);
    a2 = *(const bf16x8_t*)(La + aBase + 2 * 1024 + ks1);
    a3 = *(const bf16x8_t*)(La + aBase + 3 * 1024 + ks1);
    __builtin_amdgcn_s_setprio(1);
    acc[0][0] = __builtin_amdgcn_mfma_f32_16x16x32_bf16(a0, c0, acc[0][0], 0, 0, 0);
    acc[0][1] = __builtin_amdgcn_mfma_f32_16x16x32_bf16(a0, c1, acc[0][1], 0, 0, 0);
    acc[0][2] = __builtin_amdgcn_mfma_f32_16x16x32_bf16(a0, c2, acc[0][2], 0, 0, 0);
    acc[0][3] = __builtin_amdgcn_mfma_f32_16x16x32_bf16(a0, c3, acc[0][3], 0, 0, 0);
    acc[1][0] = __builtin_amdgcn_mfma_f32_16x16x32_bf16(a1, c0, acc[1][0], 0, 0, 0);
    acc[1][1] = __builtin_amdgcn_mfma_f32_16x16x32_bf16(a1, c1, acc[1][1], 0, 0, 0);
    acc[1][2] = __builtin_amdgcn_mfma_f32_16x16x32_bf16(a1, c2, acc[1][2], 0, 0, 0);
    acc[1][3] = __builtin_amdgcn_mfma_f32_16x16x32_bf16(a1, c3, acc[1][3], 0, 0, 0);
    acc[2][0] = __builtin_amdgcn_mfma_f32_16x16x32_bf16(a2, c0, acc[2][0], 0, 0, 0);
    acc[2][1] = __builtin_amdgcn_mfma_f32_16x16x32_bf16(a2, c1, acc[2][1], 0, 0, 0);
    acc[2][2] = __builtin_amdgcn_mfma_f32_16x16x32_bf16(a2, c2, acc[2][2], 0, 0, 0);
    acc[2][3] = __builtin_amdgcn_mfma_f32_16x16x32_bf16(a2, c3, acc[2][3], 0, 0, 0);
    acc[3][0] = __builtin_amdgcn_mfma_f32_16x16x32_bf16(a3, c0, acc[3][0], 0, 0, 0);
    acc[3][1] = __builtin_amdgcn_mfma_f32_16x16x32_bf16(a3, c1, acc[3][1], 0, 0, 0);
    acc[3][2] = __builtin_amdgcn_mfma_f32_16x16x32_bf16(a3, c2, acc[3][2], 0, 0, 0);
    acc[3][3] = __builtin_amdgcn_mfma_f32_16x16x32_bf16(a3, c3, acc[3][3], 0, 0, 0);
    __builtin_amdgcn_s_setprio(0);

    // ---- phase 2: A m4-7 kk0 ----
    a0 = *(const bf16x8_t*)(La + aBase + 4 * 1024 + ks0);
    a1 = *(const bf16x8_t*)(La + aBase + 5 * 1024 + ks0);
    a2 = *(const bf16x8_t*)(La + aBase + 6 * 1024 + ks0);
    a3 = *(const bf16x8_t*)(La + aBase + 7 * 1024 + ks0);
    __builtin_amdgcn_s_setprio(1);
    acc[4][0] = __builtin_amdgcn_mfma_f32_16x16x32_bf16(a0, b0, acc[4][0], 0, 0, 0);
    acc[4][1] = __builtin_amdgcn_mfma_f32_16x16x32_bf16(a0, b1, acc[4][1], 0, 0, 0);
    acc[4][2] = __builtin_amdgcn_mfma_f32_16x16x32_bf16(a0, b2, acc[4][2], 0, 0, 0);
    acc[4][3] = __builtin_amdgcn_mfma_f32_16x16x32_bf16(a0, b3, acc[4][3], 0, 0, 0);
    acc[5][0] = __builtin_amdgcn_mfma_f32_16x16x32_bf16(a1, b0, acc[5][0], 0, 0, 0);
    acc[5][1] = __builtin_amdgcn_mfma_f32_16x16x32_bf16(a1, b1, acc[5][1], 0, 0, 0);
    acc[5][2] = __builtin_amdgcn_mfma_f32_16x16x32_bf16(a1, b2, acc[5][2], 0, 0, 0);
    acc[5][3] = __builtin_amdgcn_mfma_f32_16x16x32_bf16(a1, b3, acc[5][3], 0, 0, 0);
    acc[6][0] = __builtin_amdgcn_mfma_f32_16x16x32_bf16(a2, b0, acc[6][0], 0, 0, 0);
    acc[6][1] = __builtin_amdgcn_mfma_f32_16x16x32_bf16(a2, b1, acc[6][1], 0, 0, 0);
    acc[6][2] = __builtin_amdgcn_mfma_f32_16x16x32_bf16(a2, b2, acc[6][2], 0, 0, 0);
    acc[6][3] = __builtin_amdgcn_mfma_f32_16x16x32_bf16(a2, b3, acc[6][3], 0, 0, 0);
    acc[7][0] = __builtin_amdgcn_mfma_f32_16x16x32_bf16(a3, b0, acc[7][0], 0, 0, 0);
    acc[7][1] = __builtin_amdgcn_mfma_f32_16x16x32_bf16(a3, b1, acc[7][1], 0, 0, 0);
    acc[7][2] = __builtin_amdgcn_mfma_f32_16x16x32_bf16(a3, b2, acc[7][2], 0, 0, 0);
    acc[7][3] = __builtin_amdgcn_mfma_f32_16x16x32_bf16(a3, b3, acc[7][3], 0, 0, 0);
    __builtin_amdgcn_s_setprio(0);

    // ---- phase 3: A m4-7 kk1 ----
    a0 = *(const bf16x8_t*)(La + aBase + 4 * 1024 + ks1);
    a1 = *(const bf16x8_t*)(La + aBase + 5 * 1024 + ks1);
    a2 = *(const bf16x8_t*)(La + aBase + 6 * 1024 + ks1);
    a3 = *(const bf16x8_t*)(La + aBase + 7 * 1024 + ks1);
    __builtin_amdgcn_s_setprio(1);
    acc[4][0] = __builtin_amdgcn_mfma_f32_16x16x32_bf16(a0, c0, acc[4][0], 0, 0, 0);
    acc[4][1] = __builtin_amdgcn_mfma_f32_16x16x32_bf16(a0, c1, acc[4][1], 0, 0, 0);
    acc[4][2] = __builtin_amdgcn_mfma_f32_16x16x32_bf16(a0, c2, acc[4][2], 0, 0, 0);
    acc[4][3] = __builtin_amdgcn_mfma_f32_16x16x32_bf16(a0, c3, acc[4][3], 0, 0, 0);
    acc[5][0] = __builtin_amdgcn_mfma_f32_16x16x32_bf16(a1, c0, acc[5][0], 0, 0, 0);
    acc[5][1] = __builtin_amdgcn_mfma_f32_16x16x32_bf16(a1, c1, acc[5][1], 0, 0, 0);
    acc[5][2] = __builtin_amdgcn_mfma_f32_16x16x32_bf16(a1, c2, acc[5][2], 0, 0, 0);
    acc[5][3] = __builtin_amdgcn_mfma_f32_16x16x32_bf16(a1, c3, acc[5][3], 0, 0, 0);
    acc[6][0] = __builtin_amdgcn_mfma_f32_16x16x32_bf16(a2, c0, acc[6][0], 0, 0, 0);
    acc[6][1] = __builtin_amdgcn_mfma_f32_16x16x32_bf16(a2, c1, acc[6][1], 0, 0, 0);
    acc[6][2] = __builtin_amdgcn_mfma_f32_16x16x32_bf16(a2, c2, acc[6][2], 0, 0, 0);
    acc[6][3] = __builtin_amdgcn_mfma_f32_16x16x32_bf16(a2, c3, acc[6][3], 0, 0, 0);
    acc[7][0] = __builtin_amdgcn_mfma_f32_16x16x32_bf16(a3, c0, acc[7][0], 0, 0, 0);
    acc[7][1] = __builtin_amdgcn_mfma_f32_16x16x32_bf16(a3, c1, acc[7][1], 0, 0, 0);
    acc[7][2] = __builtin_amdgcn_mfma_f32_16x16x32_bf16(a3, c2, acc[7][2], 0, 0, 0);
    acc[7][3] = __builtin_amdgcn_mfma_f32_16x16x32_bf16(a3, c3, acc[7][3], 0, 0, 0);
    __builtin_amdgcn_s_setprio(0);

    SBAR();  // all waves done reading buf[cur]
    if (t + 2 < H_DIM / 64) {
      STAGE((t + 2) * 64, cur);  // overwrite freed buffer
      VMCNT8();                  // tile t+1 fully landed; t+2's 8 in flight
    } else {
      VMCNT0();                  // tail: drain
    }
    SBAR();  // all waves certified their slices
  }
#undef STAGE

  // ---- fused LoRA-B epilogue: acc += u[row] . lora_b[l][:, col] ----
  const int l = lora_of(indices, row0);
  float* uL = (float*)lds;         // [256][16] f32, 16KB
  float* bL = (float*)lds + 4096;  // [16][256] f32, 16KB
  {
    const float* ug = u + (size_t)row0 * 16;
    *(float4*)(uL + tid * 8) = *(const float4*)(ug + tid * 8);
    *(float4*)(uL + tid * 8 + 4) = *(const float4*)(ug + tid * 8 + 4);
    int br = tid >> 5, bc = (tid & 31) * 8;
    const float* bg = lora_b + ((size_t)l * R_DIM + br) * O_DIM + col0 + bc;
    *(float4*)(bL + br * 256 + bc) = *(const float4*)bg;
    *(float4*)(bL + br * 256 + bc + 4) = *(const float4*)(bg + 4);
  }
  SBAR();

  const int cl0 = wc * 64 + (lane & 15);
  const int rl0 = wr * 128 + (lane >> 4) * 4;
#pragma unroll
  for (int r = 0; r < 16; ++r) {
    float b0 = bL[r * 256 + cl0];
    float b1 = bL[r * 256 + cl0 + 16];
    float b2 = bL[r * 256 + cl0 + 32];
    float b3 = bL[r * 256 + cl0 + 48];
#pragma unroll
    for (int m = 0; m < 8; ++m)
#pragma unroll
      for (int q = 0; q < 4; ++q) {
        float uv = uL[(rl0 + m * 16 + q) * 16 + r];
        acc[m][0][q] += uv * b0;
        acc[m][1][q] += uv * b1;
        acc[m][2][q] += uv * b2;
        acc[m][3][q] += uv * b3;
      }
  }

  float bv[4];
#pragma unroll
  for (int n = 0; n < 4; ++n) bv[n] = bias[col0 + cl0 + n * 16];
#pragma unroll
  for (int m = 0; m < 8; ++m)
#pragma unroll
    for (int n = 0; n < 4; ++n)
#pragma unroll
      for (int q = 0; q < 4; ++q) {
        int row = row0 + rl0 + m * 16 + q;
        out[(size_t)row * O_DIM + (col0 + cl0 + n * 16)] = acc[m][n][q] + bv[n];
      }
}

extern "C" void kernel_launch(void* const* d_in, const int* in_sizes, int n_in,
                              void* d_out, int out_size, void* d_ws, size_t ws_size,
                              hipStream_t stream) {
  const float* x      = (const float*)d_in[0];
  const float* weight = (const float*)d_in[1];
  const float* bias   = (const float*)d_in[2];
  const float* lora_a = (const float*)d_in[3];
  const float* lora_b = (const float*)d_in[4];
  const int*   indices = (const int*)d_in[5];
  float* out = (float*)d_out;

  // workspace: [Xb 32MB][Wb 32MB][u 256KB][aTb 1MB]
  unsigned short* Xb = (unsigned short*)d_ws;
  unsigned short* Wb = Xb + (size_t)T_DIM * H_DIM;
  float* u = (float*)(Wb + (size_t)O_DIM * H_DIM);
  unsigned short* aTb = (unsigned short*)(u + (size_t)T_DIM * 16);

  hipFuncSetAttribute((const void*)gemm256,
                      hipFuncAttributeMaxDynamicSharedMemorySize, 131072);

  prep1_kernel<<<128 + 8192, 256, 0, stream>>>(x, lora_a, Xb, aTb);
  prep2_kernel<<<32 + 8192, 256, 0, stream>>>(weight, Xb, aTb, indices, Wb, u);
  gemm256<<<dim3(O_DIM / 256, T_DIM / 256), 512, 131072, stream>>>(
      Xb, Wb, bias, lora_b, indices, u, out);
}